// Round 10
// baseline (581.435 us; speedup 1.0000x reference)
//
#include <hip/hip_runtime.h>
#include <cstdint>

typedef int i32x4 __attribute__((ext_vector_type(4)));
typedef int i32x16 __attribute__((ext_vector_type(16)));

#define M_DIM 8192
#define N_DIM 11008
#define K_DIM 4096
#define K32   (K_DIM / 32)   // 128 k32-fragments per row-block
#define NTILES 64            // K-tiles of BK=64 (2 k32 each)

// ws layout (bytes)
#define WS_AMAX_OFF   0                      // 1024 floats
#define WS_WSUM_OFF   4096                   // 1024 doubles
#define WS_SCALES_OFF 12288                  // 4 floats
#define WS_QX_OFF     16384                  // 8192*4096 int8 (fragment-major)
#define WS_TW_OFF     (16384 + 33554432)     // 11008*4096 int8 (fragment-major)

#define SCHED_FENCE() __builtin_amdgcn_sched_barrier(0)

__device__ __forceinline__ void gload_lds16(const void* g, void* l) {
  __builtin_amdgcn_global_load_lds(
      (const __attribute__((address_space(1))) unsigned int*)g,
      (__attribute__((address_space(3))) unsigned int*)l, 16, 0, 0);
}

// ---------------- reductions ----------------

__global__ void reduce_amax(const float* __restrict__ x, float* __restrict__ partial, int n4) {
  const float4* xv = (const float4*)x;
  float m = 0.f;
  for (long i = (long)blockIdx.x * blockDim.x + threadIdx.x; i < n4;
       i += (long)gridDim.x * blockDim.x) {
    float4 v = xv[i];
    m = fmaxf(m, fmaxf(fmaxf(fabsf(v.x), fabsf(v.y)), fmaxf(fabsf(v.z), fabsf(v.w))));
  }
  __shared__ float sm[256];
  sm[threadIdx.x] = m;
  __syncthreads();
  for (int s = 128; s > 0; s >>= 1) {
    if (threadIdx.x < s) sm[threadIdx.x] = fmaxf(sm[threadIdx.x], sm[threadIdx.x + s]);
    __syncthreads();
  }
  if (threadIdx.x == 0) partial[blockIdx.x] = sm[0];
}

__global__ void reduce_wsum(const float* __restrict__ w, double* __restrict__ partial, int n4) {
  const float4* wv = (const float4*)w;
  double acc = 0.0;
  for (long i = (long)blockIdx.x * blockDim.x + threadIdx.x; i < n4;
       i += (long)gridDim.x * blockDim.x) {
    float4 v = wv[i];
    acc += (double)fabsf(v.x) + (double)fabsf(v.y) + (double)fabsf(v.z) + (double)fabsf(v.w);
  }
  __shared__ double sd[256];
  sd[threadIdx.x] = acc;
  __syncthreads();
  for (int s = 128; s > 0; s >>= 1) {
    if (threadIdx.x < s) sd[threadIdx.x] += sd[threadIdx.x + s];
    __syncthreads();
  }
  if (threadIdx.x == 0) partial[blockIdx.x] = sd[0];
}

__global__ void finalize_scales(const float* __restrict__ amax_p,
                                const double* __restrict__ wsum_p,
                                float* __restrict__ scales) {
  __shared__ float sm[1024];
  __shared__ double sd[1024];
  const int t = threadIdx.x;
  sm[t] = amax_p[t];
  sd[t] = wsum_p[t];
  __syncthreads();
  for (int s = 512; s > 0; s >>= 1) {
    if (t < s) {
      sm[t] = fmaxf(sm[t], sm[t + s]);
      sd[t] += sd[t + s];
    }
    __syncthreads();
  }
  if (t == 0) {
    float act_scale = fmaxf(sm[0] / 127.0f, 1e-8f);
    float w_scale = (float)(sd[0] / (double)((long long)N_DIM * K_DIM)) + 1e-8f;
    scales[0] = act_scale;
    scales[1] = w_scale;
    scales[2] = act_scale * w_scale;
  }
}

// ---------------- quantize + fragment-major pack ----------------
// Layout: qp[r32][k32][lane64][16B]; lane l byte b = elem(row r32*32 + (l&31),
//   k = k32*32 + (l>>5)*16 + b)  — exactly the mfma_i32_32x32x32_i8 A/B operand.

__device__ __forceinline__ int quant_clip(float v, float s, float lim) {
  float r = rintf(v / s);                 // round-half-even, matches jnp.round
  r = fminf(fmaxf(r, -lim), lim);
  return (int)r;
}

template <int LIM_IS_W>
__global__ void quant_pack(const float* __restrict__ src, const float* __restrict__ scales,
                           int8_t* __restrict__ qp) {
  __shared__ __align__(16) int8_t buf[32 * 144];   // 32 rows x 128B, stride 144
  const float s = scales[LIM_IS_W ? 1 : 0];
  const float lim = LIM_IS_W ? 1.f : 127.f;
  const int br = blockIdx.x >> 5;          // row-block (32 rows)
  const int bk = blockIdx.x & 31;          // k-block (128 cols)
  const int t = threadIdx.x;

  // phase 1: quantize 32x128 into LDS
  const int row = t >> 3, kc = (t & 7) << 4;
  const float4* sp = (const float4*)(src + ((long)(br * 32 + row)) * K_DIM + bk * 128 + kc);
  i32x4 pk;
#pragma unroll
  for (int j = 0; j < 4; ++j) {
    float4 v = sp[j];
    int b0 = quant_clip(v.x, s, lim);
    int b1 = quant_clip(v.y, s, lim);
    int b2 = quant_clip(v.z, s, lim);
    int b3 = quant_clip(v.w, s, lim);
    pk[j] = (b0 & 255) | ((b1 & 255) << 8) | ((b2 & 255) << 16) | (b3 << 24);
  }
  *(i32x4*)(buf + row * 144 + kc) = pk;
  __syncthreads();

  // phase 2: emit 4 fragments (1KB each), coalesced
  const int g = t >> 6, l = t & 63;
  i32x4 fr = *(const i32x4*)(buf + (l & 31) * 144 + g * 32 + ((l >> 5) << 4));
  *((i32x4*)(qp + ((long)br * K32 + bk * 4 + g) * 1024) + l) = fr;
}

// ---------------- int8 GEMM: 256x256 tile, BK=64, counted-vmcnt (no drain) ----------------
// 8 waves (2m x 4n), per-wave 128x64 = acc[4][2] of 32x32 i32 frags, 16 MFMA/iter.
// Identical to the passing r9 structure EXCEPT the per-iter sync:
//   r9: __syncthreads() at iter end  => full vmcnt(0) lgkmcnt(0) drain every iter
//       (m218: drain-vs-counted costs 38-73%).
//   r10: top-of-iter `s_waitcnt vmcnt(4)` + raw s_barrier.
// Ledger (VMEM issue order pinned A-then-B by sched_barrier(0); no asm loads):
//   at iter-t top outstanding = [stageA(t):2 oldest, loadB(t):4]  (loadB(t-1)
//   retired by the compiler's own counted wait before iter t-1's MFMAs).
//   vmcnt(4) -> stageA(t)'s LDS writes landed; s_barrier -> landed for ALL waves;
//   loadB(t) stays in flight (compiler waits before first MFMA use).
//   Overwrite hazard: stageA(t+1) targets the buffer whose readers (iter-t
//   ds_reads) retired before their own MFMA issue, which precedes the barrier.

__global__ __launch_bounds__(512, 2) void gemm_i8(const int8_t* __restrict__ qxp,
                                                  const int8_t* __restrict__ twp,
                                                  const float* __restrict__ scales,
                                                  float* __restrict__ out) {
  __shared__ __align__(16) int8_t lds[2][16384];

  const int tid = threadIdx.x;
  const int l = tid & 63;
  const int w = tid >> 6;
  const int lane31 = l & 31;
  const int khalf = l >> 5;

  // ---- block -> tile mapping, 2D XCD chunk (bijective: 1376 = 8*172) ----
  const int bid = blockIdx.x;
  const int xcd = bid & 7;
  const int local = bid >> 3;               // 0..171
  const int ni = local >> 2;                // 0..42
  const int mi = (xcd << 2) + (local & 3);  // 0..31
  const long row0 = (long)mi << 8;
  const long col0 = (long)ni << 8;

  // ---- A staging: wave w stages r32 = mi*8+w (per-lane global src, uniform LDS dest) ----
  const int8_t* aSrc = qxp + ((long)(mi * 8 + w) * K32) * 1024 + l * 16;
  auto stageA = [&](int slot, int kt) {
    gload_lds16(aSrc + (long)(2 * kt) * 1024, &lds[slot][w * 2048]);
    gload_lds16(aSrc + (long)(2 * kt + 1) * 1024, &lds[slot][w * 2048 + 1024]);
  };

  // ---- B plain loads: wave w covers n32 = ni*8 + (w&3)*2 + {0,1} ----
  const int8_t* bSrc0 = twp + ((long)(ni * 8 + (w & 3) * 2) * K32) * 1024 + l * 16;
  const int8_t* bSrc1 = bSrc0 + (long)K32 * 1024;
  auto loadB = [&](i32x4 (&dst)[4], int kt) {          // dst[nf*2+sl]
    const long o = (long)(2 * kt) * 1024;
    dst[0] = *(const i32x4*)(bSrc0 + o);
    dst[1] = *(const i32x4*)(bSrc0 + o + 1024);
    dst[2] = *(const i32x4*)(bSrc1 + o);
    dst[3] = *(const i32x4*)(bSrc1 + o + 1024);
  };

  const int aRd = ((w >> 2) * 8) * 1024 + l * 16;      // + (mf*2+sl)*1024

  i32x16 acc[4][2];
#pragma unroll
  for (int mf = 0; mf < 4; ++mf)
#pragma unroll
    for (int nf = 0; nf < 2; ++nf)
#pragma unroll
      for (int e = 0; e < 16; ++e) acc[mf][nf][e] = 0;

  auto body = [&](int t, i32x4 (&bcur)[4], i32x4 (&bnext)[4]) {
    const int cur = t & 1;
    // ---- top-of-iter sync (counted, never a full drain) ----
    asm volatile("s_waitcnt vmcnt(4)" ::: "memory");   // stageA(t) landed
    __builtin_amdgcn_s_barrier();                      // ...for all waves
    asm volatile("" ::: "memory");
    SCHED_FENCE();
    const int ktn = (t + 1 < NTILES) ? t + 1 : NTILES - 1;
    stageA(cur ^ 1, ktn);                  // 2 VMEM (oldest of next iter's 6)
    SCHED_FENCE();                         // pin A before B in issue order
    loadB(bnext, ktn);                     // 4 VMEM (compiler-tracked)
    SCHED_FENCE();
    const int8_t* buf = lds[cur];
    i32x4 af[4][2];
#pragma unroll
    for (int mf = 0; mf < 4; ++mf)
#pragma unroll
      for (int sl = 0; sl < 2; ++sl)
        af[mf][sl] = *(const i32x4*)(buf + aRd + (mf * 2 + sl) * 1024);
    __builtin_amdgcn_s_setprio(1);
#pragma unroll
    for (int mf = 0; mf < 4; ++mf) {
      acc[mf][0] = __builtin_amdgcn_mfma_i32_32x32x32_i8(af[mf][0], bcur[0], acc[mf][0], 0, 0, 0);
      acc[mf][1] = __builtin_amdgcn_mfma_i32_32x32x32_i8(af[mf][0], bcur[2], acc[mf][1], 0, 0, 0);
      acc[mf][0] = __builtin_amdgcn_mfma_i32_32x32x32_i8(af[mf][1], bcur[1], acc[mf][0], 0, 0, 0);
      acc[mf][1] = __builtin_amdgcn_mfma_i32_32x32x32_i8(af[mf][1], bcur[3], acc[mf][1], 0, 0, 0);
    }
    __builtin_amdgcn_s_setprio(0);
  };

  // ---- prologue: A(0) then B(0) in flight (VMEM order pinned) ----
  i32x4 bEv[4], bOd[4];
  stageA(0, 0);
  SCHED_FENCE();
  loadB(bEv, 0);
  SCHED_FENCE();

  for (int tp = 0; tp < NTILES / 2; ++tp) {
    body(2 * tp, bEv, bOd);
    body(2 * tp + 1, bOd, bEv);
  }

  // ---- epilogue: C/D 32x32 layout: col=lane&31, row=(reg&3)+8*(reg>>2)+4*(lane>>5) ----
  const float osc = scales[2];
  const int rbase = khalf << 2;
#pragma unroll
  for (int mf = 0; mf < 4; ++mf)
#pragma unroll
    for (int nf = 0; nf < 2; ++nf)
#pragma unroll
      for (int reg = 0; reg < 16; ++reg) {
        int rr = (w >> 2) * 128 + mf * 32 + rbase + (reg & 3) + ((reg >> 2) << 3);
        int cc = (w & 3) * 64 + nf * 32 + lane31;
        out[(row0 + rr) * (long)N_DIM + (col0 + cc)] = (float)acc[mf][nf][reg] * osc;
      }
}

// ---------------- launch ----------------

extern "C" void kernel_launch(void* const* d_in, const int* in_sizes, int n_in,
                              void* d_out, int out_size, void* d_ws, size_t ws_size,
                              hipStream_t stream) {
  const float* x = (const float*)d_in[0];   // [4,2048,4096]
  const float* W = (const float*)d_in[1];   // [11008,4096]
  float* out = (float*)d_out;               // [4,2048,11008]

  char* ws = (char*)d_ws;
  float*  amax_p = (float*)(ws + WS_AMAX_OFF);
  double* wsum_p = (double*)(ws + WS_WSUM_OFF);
  float*  scales = (float*)(ws + WS_SCALES_OFF);
  int8_t* qxp = (int8_t*)(ws + WS_QX_OFF);
  int8_t* twp = (int8_t*)(ws + WS_TW_OFF);

  reduce_amax<<<1024, 256, 0, stream>>>(x, amax_p, (M_DIM * (long)K_DIM) / 4);
  reduce_wsum<<<1024, 256, 0, stream>>>(W, wsum_p, (N_DIM * (long)K_DIM) / 4);
  finalize_scales<<<1, 1024, 0, stream>>>(amax_p, wsum_p, scales);
  quant_pack<0><<<(M_DIM / 32) * 32, 256, 0, stream>>>(x, scales, qxp);
  quant_pack<1><<<(N_DIM / 32) * 32, 256, 0, stream>>>(W, scales, twp);

  const int grid = (M_DIM / 256) * (N_DIM / 256);   // 32*43 = 1376 = 8*172
  gemm_i8<<<grid, 512, 0, stream>>>(qxp, twp, scales, out);
}

// Round 11
// 551.781 us; speedup vs baseline: 1.0537x; 1.0537x over previous
//
#include <hip/hip_runtime.h>
#include <cstdint>

typedef int i32x4 __attribute__((ext_vector_type(4)));
typedef int i32x16 __attribute__((ext_vector_type(16)));

#define M_DIM 8192
#define N_DIM 11008
#define K_DIM 4096
#define K32   (K_DIM / 32)   // 128 k32-fragments per row-block
#define NTILES 64            // K-tiles of BK=64 (2 k32 each)

// ws layout (bytes)
#define WS_AMAX_OFF   0                      // 1024 floats
#define WS_WSUM_OFF   4096                   // 1024 doubles
#define WS_SCALES_OFF 12288                  // 4 floats
#define WS_QX_OFF     16384                  // 8192*4096 int8 (fragment-major)
#define WS_TW_OFF     (16384 + 33554432)     // 11008*4096 int8 (fragment-major)

__device__ __forceinline__ void gload_lds16(const void* g, void* l) {
  __builtin_amdgcn_global_load_lds(
      (const __attribute__((address_space(1))) unsigned int*)g,
      (__attribute__((address_space(3))) unsigned int*)l, 16, 0, 0);
}

// ---------------- reductions ----------------

__global__ void reduce_amax(const float* __restrict__ x, float* __restrict__ partial, int n4) {
  const float4* xv = (const float4*)x;
  float m = 0.f;
  for (long i = (long)blockIdx.x * blockDim.x + threadIdx.x; i < n4;
       i += (long)gridDim.x * blockDim.x) {
    float4 v = xv[i];
    m = fmaxf(m, fmaxf(fmaxf(fabsf(v.x), fabsf(v.y)), fmaxf(fabsf(v.z), fabsf(v.w))));
  }
  __shared__ float sm[256];
  sm[threadIdx.x] = m;
  __syncthreads();
  for (int s = 128; s > 0; s >>= 1) {
    if (threadIdx.x < s) sm[threadIdx.x] = fmaxf(sm[threadIdx.x], sm[threadIdx.x + s]);
    __syncthreads();
  }
  if (threadIdx.x == 0) partial[blockIdx.x] = sm[0];
}

__global__ void reduce_wsum(const float* __restrict__ w, double* __restrict__ partial, int n4) {
  const float4* wv = (const float4*)w;
  double acc = 0.0;
  for (long i = (long)blockIdx.x * blockDim.x + threadIdx.x; i < n4;
       i += (long)gridDim.x * blockDim.x) {
    float4 v = wv[i];
    acc += (double)fabsf(v.x) + (double)fabsf(v.y) + (double)fabsf(v.z) + (double)fabsf(v.w);
  }
  __shared__ double sd[256];
  sd[threadIdx.x] = acc;
  __syncthreads();
  for (int s = 128; s > 0; s >>= 1) {
    if (threadIdx.x < s) sd[threadIdx.x] += sd[threadIdx.x + s];
    __syncthreads();
  }
  if (threadIdx.x == 0) partial[blockIdx.x] = sd[0];
}

__global__ void finalize_scales(const float* __restrict__ amax_p,
                                const double* __restrict__ wsum_p,
                                float* __restrict__ scales) {
  __shared__ float sm[1024];
  __shared__ double sd[1024];
  const int t = threadIdx.x;
  sm[t] = amax_p[t];
  sd[t] = wsum_p[t];
  __syncthreads();
  for (int s = 512; s > 0; s >>= 1) {
    if (t < s) {
      sm[t] = fmaxf(sm[t], sm[t + s]);
      sd[t] += sd[t + s];
    }
    __syncthreads();
  }
  if (t == 0) {
    float act_scale = fmaxf(sm[0] / 127.0f, 1e-8f);
    float w_scale = (float)(sd[0] / (double)((long long)N_DIM * K_DIM)) + 1e-8f;
    scales[0] = act_scale;
    scales[1] = w_scale;
    scales[2] = act_scale * w_scale;
  }
}

// ---------------- quantize + fragment-major pack ----------------
// Layout: qp[r32][k32][lane64][16B]; lane l byte b = elem(row r32*32 + (l&31),
//   k = k32*32 + (l>>5)*16 + b)  — exactly the mfma_i32_32x32x32_i8 A/B operand.

__device__ __forceinline__ int quant_clip(float v, float s, float lim) {
  float r = rintf(v / s);                 // round-half-even, matches jnp.round
  r = fminf(fmaxf(r, -lim), lim);
  return (int)r;
}

template <int LIM_IS_W>
__global__ void quant_pack(const float* __restrict__ src, const float* __restrict__ scales,
                           int8_t* __restrict__ qp) {
  __shared__ __align__(16) int8_t buf[32 * 144];   // 32 rows x 128B, stride 144
  const float s = scales[LIM_IS_W ? 1 : 0];
  const float lim = LIM_IS_W ? 1.f : 127.f;
  const int br = blockIdx.x >> 5;          // row-block (32 rows)
  const int bk = blockIdx.x & 31;          // k-block (128 cols)
  const int t = threadIdx.x;

  // phase 1: quantize 32x128 into LDS
  const int row = t >> 3, kc = (t & 7) << 4;
  const float4* sp = (const float4*)(src + ((long)(br * 32 + row)) * K_DIM + bk * 128 + kc);
  i32x4 pk;
#pragma unroll
  for (int j = 0; j < 4; ++j) {
    float4 v = sp[j];
    int b0 = quant_clip(v.x, s, lim);
    int b1 = quant_clip(v.y, s, lim);
    int b2 = quant_clip(v.z, s, lim);
    int b3 = quant_clip(v.w, s, lim);
    pk[j] = (b0 & 255) | ((b1 & 255) << 8) | ((b2 & 255) << 16) | (b3 << 24);
  }
  *(i32x4*)(buf + row * 144 + kc) = pk;
  __syncthreads();

  // phase 2: emit 4 fragments (1KB each), coalesced
  const int g = t >> 6, l = t & 63;
  i32x4 fr = *(const i32x4*)(buf + (l & 31) * 144 + g * 32 + ((l >> 5) << 4));
  *((i32x4*)(qp + ((long)br * K32 + bk * 4 + g) * 1024) + l) = fr;
}

// ---------------- int8 GEMM: 128x256 tile, BK=64, 2 blocks/CU (drift) ----------------
// 8 waves (2m x 4n), per-wave 64x64 = acc[2][2] of 32x32 i32 frags (64 regs).
// __launch_bounds__(512,4): <=128 VGPR -> 4 waves/SIMD from TWO independent
// blocks per CU. Convoy-breaker: the two blocks' barrier phases drift, so one
// block's ds_read/VMEM phase overlaps the other's MFMA phase on every SIMD
// (r2-r10 lesson: one barrier-locked block/CU serializes LDS and MFMA pipes
// regardless of sync scheme — drain/counted/ring all ~40% MfmaUtil).
// A: fragment-major qxp -> gload_lds (1 per wave per iter, wave-uniform dest),
//    dbuf 2x8KB. B: fragment-major twp -> plain i32x4 reg loads 1 tile ahead.
// Sync: plain __syncthreads per iter (r9-verified skeleton, no inline asm).

__global__ __launch_bounds__(512, 4) void gemm_i8(const int8_t* __restrict__ qxp,
                                                  const int8_t* __restrict__ twp,
                                                  const float* __restrict__ scales,
                                                  float* __restrict__ out) {
  __shared__ __align__(16) int8_t lds[2][8192];

  const int tid = threadIdx.x;
  const int l = tid & 63;
  const int w = tid >> 6;                   // 0..7: wm = w>>2, wn = w&3
  const int lane31 = l & 31;
  const int khalf = l >> 5;

  // ---- block -> tile mapping, XCD chunk (bijective: 2752 = 8*344) ----
  const int bid = blockIdx.x;
  const int xcd = bid & 7;
  const int local = bid >> 3;               // 0..343
  const int ni = local >> 3;                // 0..42   (256-col tiles)
  const int mi = (xcd << 3) + (local & 7);  // 0..63   (128-row tiles)
  const long row0 = (long)mi << 7;
  const long col0 = (long)ni << 8;

  // ---- A staging: 8 gloads/tile, 1 per wave: r32loc = w&3, k32half = w>>2 ----
  const int8_t* aSrc = qxp + ((long)(mi * 4 + (w & 3)) * K32 + (w >> 2)) * 1024 + l * 16;
  const int aDstU = (w & 3) * 2048 + (w >> 2) * 1024;   // wave-uniform
  auto stageA = [&](int slot, int kt) {
    gload_lds16(aSrc + (long)(2 * kt) * 1024, &lds[slot][aDstU]);
  };

  // ---- B reg loads: wave w covers n32 = ni*8 + (w&3)*2 + {0,1} ----
  const int8_t* bSrc0 = twp + ((long)(ni * 8 + (w & 3) * 2) * K32) * 1024 + l * 16;
  const int8_t* bSrc1 = bSrc0 + (long)K32 * 1024;
  auto loadB = [&](i32x4 (&dst)[4], int kt) {          // dst[nf*2+sl]
    const long o = (long)(2 * kt) * 1024;
    dst[0] = *(const i32x4*)(bSrc0 + o);
    dst[1] = *(const i32x4*)(bSrc0 + o + 1024);
    dst[2] = *(const i32x4*)(bSrc1 + o);
    dst[3] = *(const i32x4*)(bSrc1 + o + 1024);
  };

  // ---- A fragment reads: r32loc = (w>>2)*2 + mf, slice sl ----
  const int aRd = (w >> 2) * 4096 + l * 16;            // + mf*2048 + sl*1024

  i32x16 acc[2][2];
#pragma unroll
  for (int mf = 0; mf < 2; ++mf)
#pragma unroll
    for (int nf = 0; nf < 2; ++nf)
#pragma unroll
      for (int e = 0; e < 16; ++e) acc[mf][nf][e] = 0;

  auto body = [&](int t, i32x4 (&bcur)[4], i32x4 (&bnext)[4]) {
    const int cur = t & 1;
    const int ktn = (t + 1 < NTILES) ? t + 1 : NTILES - 1;
    stageA(cur ^ 1, ktn);                  // 1 VMEM into the freed buffer
    loadB(bnext, ktn);                     // 4 VMEM (compiler-tracked)
    const int8_t* buf = lds[cur];
    i32x4 af[2][2];
#pragma unroll
    for (int mf = 0; mf < 2; ++mf)
#pragma unroll
      for (int sl = 0; sl < 2; ++sl)
        af[mf][sl] = *(const i32x4*)(buf + aRd + mf * 2048 + sl * 1024);
    __builtin_amdgcn_s_setprio(1);
#pragma unroll
    for (int mf = 0; mf < 2; ++mf) {
      acc[mf][0] = __builtin_amdgcn_mfma_i32_32x32x32_i8(af[mf][0], bcur[0], acc[mf][0], 0, 0, 0);
      acc[mf][1] = __builtin_amdgcn_mfma_i32_32x32x32_i8(af[mf][0], bcur[2], acc[mf][1], 0, 0, 0);
      acc[mf][0] = __builtin_amdgcn_mfma_i32_32x32x32_i8(af[mf][1], bcur[1], acc[mf][0], 0, 0, 0);
      acc[mf][1] = __builtin_amdgcn_mfma_i32_32x32x32_i8(af[mf][1], bcur[3], acc[mf][1], 0, 0, 0);
    }
    __builtin_amdgcn_s_setprio(0);
    __syncthreads();                        // drains stage/loads; frees cur
  };

  // ---- prologue: tile 0 staged + B(0) loaded, fully drained ----
  i32x4 bEv[4], bOd[4];
  stageA(0, 0);
  loadB(bEv, 0);
  __syncthreads();

  for (int tp = 0; tp < NTILES / 2; ++tp) {
    body(2 * tp, bEv, bOd);
    body(2 * tp + 1, bOd, bEv);
  }

  // ---- epilogue: C/D 32x32 layout: col=lane&31, row=(reg&3)+8*(reg>>2)+4*(lane>>5) ----
  const float osc = scales[2];
  const int rbase = khalf << 2;
#pragma unroll
  for (int mf = 0; mf < 2; ++mf)
#pragma unroll
    for (int nf = 0; nf < 2; ++nf)
#pragma unroll
      for (int reg = 0; reg < 16; ++reg) {
        int rr = (w >> 2) * 64 + mf * 32 + rbase + (reg & 3) + ((reg >> 2) << 3);
        int cc = (w & 3) * 64 + nf * 32 + lane31;
        out[(row0 + rr) * (long)N_DIM + (col0 + cc)] = (float)acc[mf][nf][reg] * osc;
      }
}

// ---------------- launch ----------------

extern "C" void kernel_launch(void* const* d_in, const int* in_sizes, int n_in,
                              void* d_out, int out_size, void* d_ws, size_t ws_size,
                              hipStream_t stream) {
  const float* x = (const float*)d_in[0];   // [4,2048,4096]
  const float* W = (const float*)d_in[1];   // [11008,4096]
  float* out = (float*)d_out;               // [4,2048,11008]

  char* ws = (char*)d_ws;
  float*  amax_p = (float*)(ws + WS_AMAX_OFF);
  double* wsum_p = (double*)(ws + WS_WSUM_OFF);
  float*  scales = (float*)(ws + WS_SCALES_OFF);
  int8_t* qxp = (int8_t*)(ws + WS_QX_OFF);
  int8_t* twp = (int8_t*)(ws + WS_TW_OFF);

  reduce_amax<<<1024, 256, 0, stream>>>(x, amax_p, (M_DIM * (long)K_DIM) / 4);
  reduce_wsum<<<1024, 256, 0, stream>>>(W, wsum_p, (N_DIM * (long)K_DIM) / 4);
  finalize_scales<<<1, 1024, 0, stream>>>(amax_p, wsum_p, scales);
  quant_pack<0><<<(M_DIM / 32) * 32, 256, 0, stream>>>(x, scales, qxp);
  quant_pack<1><<<(N_DIM / 32) * 32, 256, 0, stream>>>(W, scales, twp);

  const int grid = (M_DIM / 128) * (N_DIM / 256);   // 64*43 = 2752 = 8*344
  gemm_i8<<<grid, 512, 0, stream>>>(qxp, twp, scales, out);
}